// Round 1
// baseline (398.770 us; speedup 1.0000x reference)
//
#include <hip/hip_runtime.h>

// LongformerAttention on MI355X (gfx950) — Round 0: correctness-first MFMA baseline.
// Pipeline: cvt(fp32->bf16) -> 3x GEMM (QKV, bf16 out) -> flash attention (masked,
// tile-skipped) -> GEMM (Wo, fp32 out).

#define B_   2
#define S_   2048
#define DM   1024
#define H_   16
#define DH_  64
#define NG   204            // max(1, int(S*0.1))
#define SCL2 0.1803368801111204f   // (1/sqrt(64)) * log2(e)
#define NEGF -3.0e38f

typedef unsigned short u16;
typedef unsigned int   u32;
typedef __attribute__((ext_vector_type(8))) short frag8;   // 8 x bf16 (4 VGPRs)
typedef __attribute__((ext_vector_type(4))) float f32x4;

#define MFMA16(A, Bf, C) __builtin_amdgcn_mfma_f32_16x16x32_bf16((A), (Bf), (C), 0, 0, 0)

__device__ __forceinline__ u16 f2bf(float f) {
  union { float f; u32 u; } c; c.f = f;
  u32 u = c.u + 0x7fffu + ((c.u >> 16) & 1u);   // RNE
  return (u16)(u >> 16);
}

// ---------------- fp32 -> bf16 convert (4 elems/thread) ----------------
__global__ void cvt_kernel(const float* __restrict__ src, u16* __restrict__ dst, int n4) {
  int i = blockIdx.x * blockDim.x + threadIdx.x;
  if (i < n4) {
    float4 v = ((const float4*)src)[i];
    u32 lo = (u32)f2bf(v.x) | ((u32)f2bf(v.y) << 16);
    u32 hi = (u32)f2bf(v.z) | ((u32)f2bf(v.w) << 16);
    ((uint2*)dst)[i] = make_uint2(lo, hi);
  }
}

// ---------------- GEMM: C[m,n] = sum_k A[m,k]*B[n,k] + bias[n] ----------------
// A: [M,K] bf16 row-major, B: [N,K] bf16 row-major (i.e. X @ W^T with W as given).
// Block tile 64x64, 4 waves (each 16M x 64N), K-step 64, 16x16x32 bf16 MFMA.
template <bool OUTF32>
__global__ __launch_bounds__(256) void gemm_bt(const u16* __restrict__ A,
                                               const u16* __restrict__ Bm,
                                               const float* __restrict__ bias,
                                               void* __restrict__ Cout,
                                               int M, int N, int K) {
  __shared__ u16 As[64][72];   // +8 pad: 2-way bank aliasing only (free)
  __shared__ u16 Bs[64][72];
  const int tid = threadIdx.x;
  const int wv = tid >> 6;
  const int lane = tid & 63, l15 = lane & 15, quad = lane >> 4;
  const int bm = blockIdx.y * 64, bn = blockIdx.x * 64;
  const int srow = tid >> 2, c8 = (tid & 3) * 8;   // staging: 2x16B per matrix/thread

  f32x4 acc[4] = {};
  for (int k0 = 0; k0 < K; k0 += 64) {
    const u16* ga = A + (size_t)(bm + srow) * K + k0 + c8;
    const u16* gb = Bm + (size_t)(bn + srow) * K + k0 + c8;
    uint4 a0 = *(const uint4*)ga, a1 = *(const uint4*)(ga + 32);
    uint4 b0 = *(const uint4*)gb, b1 = *(const uint4*)(gb + 32);
    *(uint4*)&As[srow][c8] = a0;  *(uint4*)&As[srow][c8 + 32] = a1;
    *(uint4*)&Bs[srow][c8] = b0;  *(uint4*)&Bs[srow][c8 + 32] = b1;
    __syncthreads();

    frag8 af0 = *(const frag8*)&As[wv * 16 + l15][quad * 8];
    frag8 af1 = *(const frag8*)&As[wv * 16 + l15][quad * 8 + 32];
#pragma unroll
    for (int nt = 0; nt < 4; ++nt) {
      frag8 bf0 = *(const frag8*)&Bs[nt * 16 + l15][quad * 8];
      frag8 bf1 = *(const frag8*)&Bs[nt * 16 + l15][quad * 8 + 32];
      acc[nt] = MFMA16(af0, bf0, acc[nt]);
      acc[nt] = MFMA16(af1, bf1, acc[nt]);
    }
    __syncthreads();
  }

#pragma unroll
  for (int nt = 0; nt < 4; ++nt) {
    int col = bn + nt * 16 + l15;
    float bv = bias[col];
#pragma unroll
    for (int r = 0; r < 4; ++r) {
      int row = bm + wv * 16 + quad * 4 + r;   // C/D: row = quad*4+reg, col = lane&15
      float v = acc[nt][r] + bv;
      if (OUTF32) ((float*)Cout)[(size_t)row * N + col] = v;
      else        ((u16*)Cout)[(size_t)row * N + col] = f2bf(v);
    }
  }
}

// ---------------- Flash attention with longformer mask ----------------
// Grid: (S/64 q-tiles, B*H). Block 256 = 4 waves; wave w owns Q rows q0+16w..+15.
// K/V staged 32 keys at a time; fully-masked k-tiles skipped.
__global__ __launch_bounds__(256) void attn_kernel(const u16* __restrict__ Q,
                                                   const u16* __restrict__ K,
                                                   const u16* __restrict__ V,
                                                   u16* __restrict__ Ctx) {
  __shared__ u16 Ks[32][72];
  __shared__ u16 Vs[32][72];
  __shared__ u16 Ps[4][16][56];   // per-wave P round-trip (C-layout -> A-layout)

  const int tid = threadIdx.x;
  const int w = tid >> 6;
  const int lane = tid & 63, l15 = lane & 15, quad = lane >> 4;
  const int q0 = blockIdx.x * 64;
  const int b = blockIdx.y / H_, h = blockIdx.y % H_;
  const int qw = q0 + w * 16;

  // Q A-fragments (held in registers for the whole block)
  const u16* qrow = Q + (size_t)(b * S_ + qw + l15) * DM + h * DH_;
  frag8 aq0 = *(const frag8*)(qrow + quad * 8);
  frag8 aq1 = *(const frag8*)(qrow + quad * 8 + 32);

  float m_run[4], l_run[4];
  f32x4 o[4] = {};
#pragma unroll
  for (int r = 0; r < 4; ++r) { m_run[r] = NEGF; l_run[r] = 0.f; }

  const int srow = tid >> 3, sc8 = (tid & 7) * 8;

  for (int kt = 0; kt < S_ / 32; ++kt) {
    const int k0 = kt * 32;
    // tile attended iff any q row is global, any k col is global, or window overlap
    bool active = (q0 < NG) || (k0 < NG) || (k0 <= q0 + 127 && k0 + 31 >= q0 - 64);
    if (!active) continue;

    const size_t gofs = (size_t)(b * S_ + k0 + srow) * DM + h * DH_ + sc8;
    *(uint4*)&Ks[srow][sc8] = *(const uint4*)(K + gofs);
    *(uint4*)&Vs[srow][sc8] = *(const uint4*)(V + gofs);
    __syncthreads();

    // scores: S = Q(16x64) @ K_tile^T(64x32) -> two 16x16 C-frags
    f32x4 sc0 = {}, sc1 = {};
    {
      frag8 bk;
      bk = *(const frag8*)&Ks[l15][quad * 8];            sc0 = MFMA16(aq0, bk, sc0);
      bk = *(const frag8*)&Ks[l15][quad * 8 + 32];       sc0 = MFMA16(aq1, bk, sc0);
      bk = *(const frag8*)&Ks[16 + l15][quad * 8];       sc1 = MFMA16(aq0, bk, sc1);
      bk = *(const frag8*)&Ks[16 + l15][quad * 8 + 32];  sc1 = MFMA16(aq1, bk, sc1);
    }

    // mask + scale (base-2 domain)
    float s0[4], s1[4], mt[4];
    const int kc0 = k0 + l15, kc1 = k0 + 16 + l15;
#pragma unroll
    for (int r = 0; r < 4; ++r) {
      int q = qw + quad * 4 + r;
      int d0 = q - kc0, d1 = q - kc1;
      bool a0 = (d0 >= -64 && d0 <= 64) || (q < NG) || (kc0 < NG);
      bool a1 = (d1 >= -64 && d1 <= 64) || (q < NG) || (kc1 < NG);
      s0[r] = a0 ? sc0[r] * SCL2 : NEGF;
      s1[r] = a1 ? sc1[r] * SCL2 : NEGF;
      mt[r] = fmaxf(s0[r], s1[r]);
    }
    // row max over the 16 lanes holding this row's keys
#pragma unroll
    for (int off = 8; off >= 1; off >>= 1)
#pragma unroll
      for (int r = 0; r < 4; ++r) mt[r] = fmaxf(mt[r], __shfl_xor(mt[r], off));

    float p0[4], p1[4], st[4];
#pragma unroll
    for (int r = 0; r < 4; ++r) {
      float mn = fmaxf(m_run[r], mt[r]);
      float al = exp2f(m_run[r] - mn);
      m_run[r] = mn;
      p0[r] = exp2f(s0[r] - mn);    // masked -> exp2(-huge) = 0 exactly
      p1[r] = exp2f(s1[r] - mn);
      st[r] = p0[r] + p1[r];
      l_run[r] *= al;
#pragma unroll
      for (int nt = 0; nt < 4; ++nt) o[nt][r] *= al;
    }
#pragma unroll
    for (int off = 8; off >= 1; off >>= 1)
#pragma unroll
      for (int r = 0; r < 4; ++r) st[r] += __shfl_xor(st[r], off);
#pragma unroll
    for (int r = 0; r < 4; ++r) l_run[r] += st[r];

    // P: C-layout -> LDS -> A-layout
#pragma unroll
    for (int r = 0; r < 4; ++r) {
      Ps[w][quad * 4 + r][l15]      = f2bf(p0[r]);
      Ps[w][quad * 4 + r][16 + l15] = f2bf(p1[r]);
    }
    __asm__ volatile("s_waitcnt lgkmcnt(0)" ::: "memory");  // wave-private region; no block barrier needed
    frag8 ap = *(const frag8*)&Ps[w][l15][quad * 8];

    // O += P(16x32) @ V(32x64): B-frag gathered from Vs rows (strided u16 reads)
#pragma unroll
    for (int nt = 0; nt < 4; ++nt) {
      frag8 bv;
#pragma unroll
      for (int j = 0; j < 8; ++j) bv[j] = (short)Vs[quad * 8 + j][nt * 16 + l15];
      o[nt] = MFMA16(ap, bv, o[nt]);
    }
    __syncthreads();
  }

#pragma unroll
  for (int r = 0; r < 4; ++r) {
    float inv = 1.0f / l_run[r];
    int row = qw + quad * 4 + r;
    u16* crow = Ctx + (size_t)(b * S_ + row) * DM + h * DH_;
#pragma unroll
    for (int nt = 0; nt < 4; ++nt)
      crow[nt * 16 + l15] = f2bf(o[nt][r] * inv);
  }
}

// ---------------- launch ----------------
extern "C" void kernel_launch(void* const* d_in, const int* in_sizes, int n_in,
                              void* d_out, int out_size, void* d_ws, size_t ws_size,
                              hipStream_t stream) {
  const float* X  = (const float*)d_in[0];
  const float* Wq = (const float*)d_in[1];
  const float* bq = (const float*)d_in[2];
  const float* Wk = (const float*)d_in[3];
  const float* bk = (const float*)d_in[4];
  const float* Wv = (const float*)d_in[5];
  const float* bv = (const float*)d_in[6];
  const float* Wo = (const float*)d_in[7];
  const float* bo = (const float*)d_in[8];
  float* out = (float*)d_out;

  u16* ws = (u16*)d_ws;
  const size_t NX = (size_t)B_ * S_ * DM;   // 4,194,304
  const size_t NW = (size_t)DM * DM;        // 1,048,576
  u16* Xb  = ws;
  u16* Wqb = Xb + NX;
  u16* Wkb = Wqb + NW;
  u16* Wvb = Wkb + NW;
  u16* Wob = Wvb + NW;
  u16* Qb  = Wob + NW;
  u16* Kb  = Qb + NX;
  u16* Vb  = Kb + NX;
  u16* Cx  = Vb + NX;   // total ~48 MB of d_ws

  cvt_kernel<<<(int)(NX / 4 / 256), 256, 0, stream>>>(X,  Xb,  (int)(NX / 4));
  cvt_kernel<<<(int)(NW / 4 / 256), 256, 0, stream>>>(Wq, Wqb, (int)(NW / 4));
  cvt_kernel<<<(int)(NW / 4 / 256), 256, 0, stream>>>(Wk, Wkb, (int)(NW / 4));
  cvt_kernel<<<(int)(NW / 4 / 256), 256, 0, stream>>>(Wv, Wvb, (int)(NW / 4));
  cvt_kernel<<<(int)(NW / 4 / 256), 256, 0, stream>>>(Wo, Wob, (int)(NW / 4));

  dim3 gg(DM / 64, (B_ * S_) / 64);
  gemm_bt<false><<<gg, 256, 0, stream>>>(Xb, Wqb, bq, Qb, B_ * S_, DM, DM);
  gemm_bt<false><<<gg, 256, 0, stream>>>(Xb, Wkb, bk, Kb, B_ * S_, DM, DM);
  gemm_bt<false><<<gg, 256, 0, stream>>>(Xb, Wvb, bv, Vb, B_ * S_, DM, DM);

  attn_kernel<<<dim3(S_ / 64, B_ * H_), 256, 0, stream>>>(Qb, Kb, Vb, Cx);

  gemm_bt<true><<<gg, 256, 0, stream>>>(Cx, Wob, bo, out, B_ * S_, DM, DM);
}

// Round 2
// 265.275 us; speedup vs baseline: 1.5032x; 1.5032x over previous
//
#include <hip/hip_runtime.h>

// LongformerAttention MI355X — Round 1.
// cvt(1 launch) -> fused QKV GEMM (m97-style: 128x128 tile, global_load_lds w/
// XOR swizzle; V written transposed) -> flash attn (64-key tiles, reg-double-
// buffered staging, vectorized PV via V^T) -> Wo GEMM (f32 out).

#define B_   2
#define S_   2048
#define DM   1024
#define H_   16
#define NG   204                     // max(1, int(S*0.1))
#define BS_  4096                    // B_*S_
#define SCL2 0.1803368801111204f     // (1/sqrt(64)) * log2(e)
#define NEGF -3.0e38f

typedef unsigned short u16;
typedef unsigned int   u32;
typedef __attribute__((ext_vector_type(8))) short frag8;   // 8 x bf16
typedef __attribute__((ext_vector_type(4))) float f32x4;

#define MFMA16(A, Bf, C) __builtin_amdgcn_mfma_f32_16x16x32_bf16((A), (Bf), (C), 0, 0, 0)
#define GLD16(g, l)                                                              \
  __builtin_amdgcn_global_load_lds((const __attribute__((address_space(1))) u32*)(g), \
                                   (__attribute__((address_space(3))) u32*)(l), 16, 0, 0)

__device__ __forceinline__ u16 f2bf(float f) {
  union { float f; u32 u; } c; c.f = f;
  u32 u = c.u + 0x7fffu + ((c.u >> 16) & 1u);   // RNE
  return (u16)(u >> 16);
}

// ---------------- fp32 -> bf16 convert, all buffers in one launch ----------------
// grid (1024, 8): chunk 0..3 = X quarters (4M elems), 4..7 = Wq,Wk,Wv,Wo (1M each)
__global__ void cvt_all(const float* __restrict__ X,  const float* __restrict__ Wq,
                        const float* __restrict__ Wk, const float* __restrict__ Wv,
                        const float* __restrict__ Wo,
                        u16* Xb, u16* Wqb, u16* Wkb, u16* Wvb, u16* Wob) {
  const int chunk = blockIdx.y;
  const float* src; u16* dst;
  if (chunk < 4)      { src = X + (size_t)chunk * 1048576; dst = Xb + (size_t)chunk * 1048576; }
  else if (chunk == 4){ src = Wq; dst = Wqb; }
  else if (chunk == 5){ src = Wk; dst = Wkb; }
  else if (chunk == 6){ src = Wv; dst = Wvb; }
  else                { src = Wo; dst = Wob; }
  int i = blockIdx.x * 256 + threadIdx.x;    // 262144 float4 per chunk
  float4 v = ((const float4*)src)[i];
  u32 lo = (u32)f2bf(v.x) | ((u32)f2bf(v.y) << 16);
  u32 hi = (u32)f2bf(v.z) | ((u32)f2bf(v.w) << 16);
  ((uint2*)dst)[i] = make_uint2(lo, hi);
}

// ---------------- m97-style GEMM mainloop: C(128x128) += A[M,K] * B[N,K]^T ----------------
// K=DM=1024, BK=64. LDS unpadded 128x64 bf16 per matrix, XOR-swizzled 16B blocks:
// stored block = row*8 + (cb ^ (row&7)); swizzle applied to the global ptr since
// global_load_lds dest is fixed at base + lane*16.
__device__ __forceinline__ void gemm_mainloop(const u16* __restrict__ A, const u16* __restrict__ Bm,
                                              int bm, int bn, u16* As, u16* Bs,
                                              f32x4 acc[4][4]) {
  const int tid = threadIdx.x;
  const int wv = tid >> 6, lane = tid & 63, l15 = lane & 15, quad = lane >> 4;
  const int wm = wv & 1, wn = wv >> 1;

  const u16* gA[4]; const u16* gB[4];
#pragma unroll
  for (int c = 0; c < 4; ++c) {
    int idx = (wv * 4 + c) * 64 + lane;          // 16B-block index 0..1023
    int r = idx >> 3;                            // tile row 0..127
    int cb = (idx & 7) ^ (r & 7);                // logical 16B col-block
    gA[c] = A  + (size_t)(bm + r) * DM + cb * 8;
    gB[c] = Bm + (size_t)(bn + r) * DM + cb * 8;
  }

  int offA[4][2], offB[4][2];                    // frag LDS byte offsets (swizzled)
#pragma unroll
  for (int i = 0; i < 4; ++i)
#pragma unroll
    for (int h = 0; h < 2; ++h) {
      int mA = wm * 64 + i * 16 + l15;
      int mB = wn * 64 + i * 16 + l15;
      int cb = (quad + h * 4) ^ (l15 & 7);
      offA[i][h] = ((mA << 3) + cb) << 4;
      offB[i][h] = ((mB << 3) + cb) << 4;
    }

  for (int k0 = 0; k0 < DM; k0 += 64) {
#pragma unroll
    for (int c = 0; c < 4; ++c) {
      GLD16(gA[c] + k0, (char*)As + (wv * 4 + c) * 1024);
      GLD16(gB[c] + k0, (char*)Bs + (wv * 4 + c) * 1024);
    }
    __syncthreads();
    frag8 af[4][2], bf[4][2];
#pragma unroll
    for (int i = 0; i < 4; ++i) {
      af[i][0] = *(const frag8*)((const char*)As + offA[i][0]);
      af[i][1] = *(const frag8*)((const char*)As + offA[i][1]);
      bf[i][0] = *(const frag8*)((const char*)Bs + offB[i][0]);
      bf[i][1] = *(const frag8*)((const char*)Bs + offB[i][1]);
    }
#pragma unroll
    for (int h = 0; h < 2; ++h)
#pragma unroll
      for (int i = 0; i < 4; ++i)
#pragma unroll
        for (int j = 0; j < 4; ++j)
          acc[i][j] = MFMA16(af[i][h], bf[j][h], acc[i][j]);
    __syncthreads();
  }
}

// Fused QKV: grid (24, 32). which = blockIdx.x/8 selects Q/K/V. V stored transposed.
__global__ __launch_bounds__(256, 3) void gemm_qkv(const u16* __restrict__ Xb,
    const u16* __restrict__ Wqb, const u16* __restrict__ Wkb, const u16* __restrict__ Wvb,
    const float* __restrict__ bq, const float* __restrict__ bk, const float* __restrict__ bv,
    u16* __restrict__ Qb, u16* __restrict__ Kb, u16* __restrict__ Vt) {
  __shared__ u16 As[8192], Bs[8192];
  const int bm = blockIdx.y * 128;
  const int which = blockIdx.x >> 3;
  const int bnl = (blockIdx.x & 7) * 128;
  const u16* W = (which == 0) ? Wqb : (which == 1) ? Wkb : Wvb;
  const float* bias = (which == 0) ? bq : (which == 1) ? bk : bv;

  f32x4 acc[4][4] = {};
  gemm_mainloop(Xb, W, bm, bnl, As, Bs, acc);

  const int tid = threadIdx.x, wv = tid >> 6, lane = tid & 63, l15 = lane & 15, quad = lane >> 4;
  const int wm = wv & 1, wn = wv >> 1;
  if (which < 2) {
    u16* O = (which == 0) ? Qb : Kb;
#pragma unroll
    for (int j = 0; j < 4; ++j) {
      int col = bnl + wn * 64 + j * 16 + l15;
      float bb = bias[col];
#pragma unroll
      for (int i = 0; i < 4; ++i) {
        int row0 = bm + wm * 64 + i * 16 + quad * 4;
#pragma unroll
        for (int r = 0; r < 4; ++r)
          O[(size_t)(row0 + r) * DM + col] = f2bf(acc[i][j][r] + bb);
      }
    }
  } else {            // V transposed: Vt[col][token], 4 consecutive tokens -> 8B store
#pragma unroll
    for (int j = 0; j < 4; ++j) {
      int col = bnl + wn * 64 + j * 16 + l15;
      float bb = bias[col];
#pragma unroll
      for (int i = 0; i < 4; ++i) {
        int row0 = bm + wm * 64 + i * 16 + quad * 4;
        u32 lo = (u32)f2bf(acc[i][j][0] + bb) | ((u32)f2bf(acc[i][j][1] + bb) << 16);
        u32 hi = (u32)f2bf(acc[i][j][2] + bb) | ((u32)f2bf(acc[i][j][3] + bb) << 16);
        *(uint2*)&Vt[(size_t)col * BS_ + row0] = make_uint2(lo, hi);
      }
    }
  }
}

// Wo GEMM: f32 out to d_out. grid (8, 32).
__global__ __launch_bounds__(256, 3) void gemm_wo(const u16* __restrict__ Cx,
    const u16* __restrict__ Wob, const float* __restrict__ bo, float* __restrict__ out) {
  __shared__ u16 As[8192], Bs[8192];
  const int bm = blockIdx.y * 128, bn = blockIdx.x * 128;
  f32x4 acc[4][4] = {};
  gemm_mainloop(Cx, Wob, bm, bn, As, Bs, acc);
  const int tid = threadIdx.x, wv = tid >> 6, lane = tid & 63, l15 = lane & 15, quad = lane >> 4;
  const int wm = wv & 1, wn = wv >> 1;
#pragma unroll
  for (int j = 0; j < 4; ++j) {
    int col = bn + wn * 64 + j * 16 + l15;
    float bb = bo[col];
#pragma unroll
    for (int i = 0; i < 4; ++i) {
      int row0 = bm + wm * 64 + i * 16 + quad * 4;
#pragma unroll
      for (int r = 0; r < 4; ++r)
        out[(size_t)(row0 + r) * DM + col] = acc[i][j][r] + bb;
    }
  }
}

// ---------------- Flash attention, 64-key tiles, V^T, reg double-buffered ----------------
__device__ __forceinline__ bool tile_active(int q0, int kt) {
  int k0 = kt * 64;
  if (q0 < NG || k0 < NG) return true;
  return (k0 <= q0 + 127) && (k0 + 63 >= q0 - 64);
}

__global__ __launch_bounds__(256) void attn_kernel(const u16* __restrict__ Q,
                                                   const u16* __restrict__ K,
                                                   const u16* __restrict__ Vt,
                                                   u16* __restrict__ Ctx) {
  __shared__ u16 Ks[64][72];     // [key][dh]
  __shared__ u16 Vs[64][72];     // transposed: [dh][key]
  __shared__ u16 Ps[4][16][72];  // per-wave P round-trip

  const int tid = threadIdx.x, w = tid >> 6, lane = tid & 63, l15 = lane & 15, quad = lane >> 4;
  const int q0 = blockIdx.x * 64;
  const int b = blockIdx.y >> 4, h = blockIdx.y & 15;
  const int qw = q0 + w * 16;

  const u16* qrow = Q + (size_t)(b * S_ + qw + l15) * DM + h * 64;
  frag8 aq0 = *(const frag8*)(qrow + quad * 8);
  frag8 aq1 = *(const frag8*)(qrow + quad * 8 + 32);

  const int sr = tid >> 2, scc = (tid & 3) * 16;
  const u16* gKbase = K  + (size_t)(b * S_ + sr) * DM + h * 64 + scc;  // + k0*DM
  const u16* gVbase = Vt + (size_t)(h * 64 + sr) * BS_ + b * S_ + scc; // + k0

  float m_run[4], l_run[4];
  f32x4 o[4] = {};
#pragma unroll
  for (int r = 0; r < 4; ++r) { m_run[r] = NEGF; l_run[r] = 0.f; }

  int kt = 0;   // tile 0 always active (global cols)
  uint4 rk0, rk1, rv0, rv1;
  {
    const u16* gk = gKbase;            rk0 = *(const uint4*)gk; rk1 = *(const uint4*)(gk + 8);
    const u16* gv = gVbase;            rv0 = *(const uint4*)gv; rv1 = *(const uint4*)(gv + 8);
  }

  while (true) {
    __syncthreads();                               // prev compute done before overwrite
    *(uint4*)&Ks[sr][scc] = rk0;  *(uint4*)&Ks[sr][scc + 8] = rk1;
    *(uint4*)&Vs[sr][scc] = rv0;  *(uint4*)&Vs[sr][scc + 8] = rv1;
    __syncthreads();

    const int k0 = kt * 64;
    int ktn = kt + 1;
    while (ktn < S_ / 64 && !tile_active(q0, ktn)) ++ktn;
    if (ktn < S_ / 64) {                           // prefetch overlaps compute
      const u16* gk = gKbase + (size_t)(ktn * 64) * DM;
      rk0 = *(const uint4*)gk; rk1 = *(const uint4*)(gk + 8);
      const u16* gv = gVbase + ktn * 64;
      rv0 = *(const uint4*)gv; rv1 = *(const uint4*)(gv + 8);
    }

    // QK^T: 4 key-groups of 16
    f32x4 scf[4] = {};
#pragma unroll
    for (int kg = 0; kg < 4; ++kg) {
      frag8 bk0 = *(const frag8*)&Ks[kg * 16 + l15][quad * 8];
      frag8 bk1 = *(const frag8*)&Ks[kg * 16 + l15][quad * 8 + 32];
      scf[kg] = MFMA16(aq0, bk0, scf[kg]);
      scf[kg] = MFMA16(aq1, bk1, scf[kg]);
    }

    // mask + scale (base-2), row max over 16 lanes
    float sv[4][4], mt[4];
#pragma unroll
    for (int r = 0; r < 4; ++r) mt[r] = NEGF;
#pragma unroll
    for (int kg = 0; kg < 4; ++kg) {
      int kc = k0 + kg * 16 + l15;
      bool kglob = kc < NG;
#pragma unroll
      for (int r = 0; r < 4; ++r) {
        int q = qw + quad * 4 + r;
        int d = q - kc;
        bool act = (d >= -64 && d <= 64) || (q < NG) || kglob;
        sv[kg][r] = act ? scf[kg][r] * SCL2 : NEGF;
        mt[r] = fmaxf(mt[r], sv[kg][r]);
      }
    }
#pragma unroll
    for (int off = 8; off; off >>= 1)
#pragma unroll
      for (int r = 0; r < 4; ++r) mt[r] = fmaxf(mt[r], __shfl_xor(mt[r], off));

    float st[4];
#pragma unroll
    for (int r = 0; r < 4; ++r) {
      float mn = fmaxf(m_run[r], mt[r]);
      float al = exp2f(m_run[r] - mn);
      m_run[r] = mn;
      l_run[r] *= al;
      float ssum = 0.f;
#pragma unroll
      for (int kg = 0; kg < 4; ++kg) {
        float p = exp2f(sv[kg][r] - mn);   // masked -> 0 exactly
        sv[kg][r] = p;
        ssum += p;
      }
      st[r] = ssum;
#pragma unroll
      for (int nt = 0; nt < 4; ++nt) o[nt][r] *= al;
    }
#pragma unroll
    for (int off = 8; off; off >>= 1)
#pragma unroll
      for (int r = 0; r < 4; ++r) st[r] += __shfl_xor(st[r], off);
#pragma unroll
    for (int r = 0; r < 4; ++r) l_run[r] += st[r];

    // P: C-layout -> per-wave LDS -> A-frags
#pragma unroll
    for (int kg = 0; kg < 4; ++kg)
#pragma unroll
      for (int r = 0; r < 4; ++r)
        Ps[w][quad * 4 + r][kg * 16 + l15] = f2bf(sv[kg][r]);
    __asm__ volatile("s_waitcnt lgkmcnt(0)" ::: "memory");   // wave-private region
    frag8 ap0 = *(const frag8*)&Ps[w][l15][quad * 8];
    frag8 ap1 = *(const frag8*)&Ps[w][l15][quad * 8 + 32];

    // O += P(16x64) @ V(64x64) via V^T rows (vector b128 reads)
#pragma unroll
    for (int nt = 0; nt < 4; ++nt) {
      frag8 bv0 = *(const frag8*)&Vs[nt * 16 + l15][quad * 8];
      frag8 bv1 = *(const frag8*)&Vs[nt * 16 + l15][quad * 8 + 32];
      o[nt] = MFMA16(ap0, bv0, o[nt]);
      o[nt] = MFMA16(ap1, bv1, o[nt]);
    }

    kt = ktn;
    if (kt >= S_ / 64) break;
  }

#pragma unroll
  for (int r = 0; r < 4; ++r) {
    float inv = 1.0f / l_run[r];
    int row = qw + quad * 4 + r;
    u16* crow = Ctx + (size_t)(b * S_ + row) * DM + h * 64;
#pragma unroll
    for (int nt = 0; nt < 4; ++nt)
      crow[nt * 16 + l15] = f2bf(o[nt][r] * inv);
  }
}

// ---------------- launch ----------------
extern "C" void kernel_launch(void* const* d_in, const int* in_sizes, int n_in,
                              void* d_out, int out_size, void* d_ws, size_t ws_size,
                              hipStream_t stream) {
  const float* X  = (const float*)d_in[0];
  const float* Wq = (const float*)d_in[1];
  const float* bq = (const float*)d_in[2];
  const float* Wk = (const float*)d_in[3];
  const float* bk = (const float*)d_in[4];
  const float* Wv = (const float*)d_in[5];
  const float* bv = (const float*)d_in[6];
  const float* Wo = (const float*)d_in[7];
  const float* bo = (const float*)d_in[8];
  float* out = (float*)d_out;

  u16* ws = (u16*)d_ws;
  const size_t NX = (size_t)BS_ * DM;   // 4,194,304
  const size_t NW = (size_t)DM * DM;    // 1,048,576
  u16* Xb  = ws;
  u16* Wqb = Xb + NX;
  u16* Wkb = Wqb + NW;
  u16* Wvb = Wkb + NW;
  u16* Wob = Wvb + NW;
  u16* Qb  = Wob + NW;
  u16* Kb  = Qb + NX;
  u16* Vt  = Kb + NX;    // [DM][BS_] transposed
  u16* Cx  = Vt + NX;

  cvt_all<<<dim3(1024, 8), 256, 0, stream>>>(X, Wq, Wk, Wv, Wo, Xb, Wqb, Wkb, Wvb, Wob);
  gemm_qkv<<<dim3(24, 32), 256, 0, stream>>>(Xb, Wqb, Wkb, Wvb, bq, bk, bv, Qb, Kb, Vt);
  attn_kernel<<<dim3(32, 32), 256, 0, stream>>>(Qb, Kb, Vt, Cx);
  gemm_wo<<<dim3(8, 32), 256, 0, stream>>>(Cx, Wob, bo, out);
}

// Round 3
// 238.578 us; speedup vs baseline: 1.6714x; 1.1119x over previous
//
#include <hip/hip_runtime.h>

// LongformerAttention MI355X — Round 2.
// attn rewritten: no LDS staging, no barriers, static-max softmax (deferred
// l-reduction), direct global->VGPR K/V^T fragments, swizzled 32-row q-strips.
// GEMM/cvt stages unchanged from Round 1.

#define B_   2
#define S_   2048
#define DM   1024
#define H_   16
#define NG   204                     // max(1, int(S*0.1))
#define BS_  4096                    // B_*S_
#define SCL2 0.1803368801111204f     // (1/sqrt(64)) * log2(e)
#define NEGF -3.0e38f

typedef unsigned short u16;
typedef unsigned int   u32;
typedef __attribute__((ext_vector_type(8))) short frag8;   // 8 x bf16
typedef __attribute__((ext_vector_type(4))) float f32x4;

#define MFMA16(A, Bf, C) __builtin_amdgcn_mfma_f32_16x16x32_bf16((A), (Bf), (C), 0, 0, 0)
#define GLD16(g, l)                                                              \
  __builtin_amdgcn_global_load_lds((const __attribute__((address_space(1))) u32*)(g), \
                                   (__attribute__((address_space(3))) u32*)(l), 16, 0, 0)

#if __has_builtin(__builtin_amdgcn_exp2f)
#define EXP2(x) __builtin_amdgcn_exp2f(x)
#else
#define EXP2(x) exp2f(x)
#endif

__device__ __forceinline__ u16 f2bf(float f) {
  union { float f; u32 u; } c; c.f = f;
  u32 u = c.u + 0x7fffu + ((c.u >> 16) & 1u);   // RNE
  return (u16)(u >> 16);
}

// ---------------- fp32 -> bf16 convert, all buffers in one launch ----------------
__global__ void cvt_all(const float* __restrict__ X,  const float* __restrict__ Wq,
                        const float* __restrict__ Wk, const float* __restrict__ Wv,
                        const float* __restrict__ Wo,
                        u16* Xb, u16* Wqb, u16* Wkb, u16* Wvb, u16* Wob) {
  const int chunk = blockIdx.y;
  const float* src; u16* dst;
  if (chunk < 4)      { src = X + (size_t)chunk * 1048576; dst = Xb + (size_t)chunk * 1048576; }
  else if (chunk == 4){ src = Wq; dst = Wqb; }
  else if (chunk == 5){ src = Wk; dst = Wkb; }
  else if (chunk == 6){ src = Wv; dst = Wvb; }
  else                { src = Wo; dst = Wob; }
  int i = blockIdx.x * 256 + threadIdx.x;
  float4 v = ((const float4*)src)[i];
  u32 lo = (u32)f2bf(v.x) | ((u32)f2bf(v.y) << 16);
  u32 hi = (u32)f2bf(v.z) | ((u32)f2bf(v.w) << 16);
  ((uint2*)dst)[i] = make_uint2(lo, hi);
}

// ---------------- m97-style GEMM mainloop (unchanged) ----------------
__device__ __forceinline__ void gemm_mainloop(const u16* __restrict__ A, const u16* __restrict__ Bm,
                                              int bm, int bn, u16* As, u16* Bs,
                                              f32x4 acc[4][4]) {
  const int tid = threadIdx.x;
  const int wv = tid >> 6, lane = tid & 63, l15 = lane & 15, quad = lane >> 4;
  const int wm = wv & 1, wn = wv >> 1;

  const u16* gA[4]; const u16* gB[4];
#pragma unroll
  for (int c = 0; c < 4; ++c) {
    int idx = (wv * 4 + c) * 64 + lane;
    int r = idx >> 3;
    int cb = (idx & 7) ^ (r & 7);
    gA[c] = A  + (size_t)(bm + r) * DM + cb * 8;
    gB[c] = Bm + (size_t)(bn + r) * DM + cb * 8;
  }

  int offA[4][2], offB[4][2];
#pragma unroll
  for (int i = 0; i < 4; ++i)
#pragma unroll
    for (int h = 0; h < 2; ++h) {
      int mA = wm * 64 + i * 16 + l15;
      int mB = wn * 64 + i * 16 + l15;
      int cb = (quad + h * 4) ^ (l15 & 7);
      offA[i][h] = ((mA << 3) + cb) << 4;
      offB[i][h] = ((mB << 3) + cb) << 4;
    }

  for (int k0 = 0; k0 < DM; k0 += 64) {
#pragma unroll
    for (int c = 0; c < 4; ++c) {
      GLD16(gA[c] + k0, (char*)As + (wv * 4 + c) * 1024);
      GLD16(gB[c] + k0, (char*)Bs + (wv * 4 + c) * 1024);
    }
    __syncthreads();
    frag8 af[4][2], bf[4][2];
#pragma unroll
    for (int i = 0; i < 4; ++i) {
      af[i][0] = *(const frag8*)((const char*)As + offA[i][0]);
      af[i][1] = *(const frag8*)((const char*)As + offA[i][1]);
      bf[i][0] = *(const frag8*)((const char*)Bs + offB[i][0]);
      bf[i][1] = *(const frag8*)((const char*)Bs + offB[i][1]);
    }
#pragma unroll
    for (int h = 0; h < 2; ++h)
#pragma unroll
      for (int i = 0; i < 4; ++i)
#pragma unroll
        for (int j = 0; j < 4; ++j)
          acc[i][j] = MFMA16(af[i][h], bf[j][h], acc[i][j]);
    __syncthreads();
  }
}

__global__ __launch_bounds__(256, 3) void gemm_qkv(const u16* __restrict__ Xb,
    const u16* __restrict__ Wqb, const u16* __restrict__ Wkb, const u16* __restrict__ Wvb,
    const float* __restrict__ bq, const float* __restrict__ bk, const float* __restrict__ bv,
    u16* __restrict__ Qb, u16* __restrict__ Kb, u16* __restrict__ Vt) {
  __shared__ u16 As[8192], Bs[8192];
  const int bm = blockIdx.y * 128;
  const int which = blockIdx.x >> 3;
  const int bnl = (blockIdx.x & 7) * 128;
  const u16* W = (which == 0) ? Wqb : (which == 1) ? Wkb : Wvb;
  const float* bias = (which == 0) ? bq : (which == 1) ? bk : bv;

  f32x4 acc[4][4] = {};
  gemm_mainloop(Xb, W, bm, bnl, As, Bs, acc);

  const int tid = threadIdx.x, wv = tid >> 6, lane = tid & 63, l15 = lane & 15, quad = lane >> 4;
  const int wm = wv & 1, wn = wv >> 1;
  if (which < 2) {
    u16* O = (which == 0) ? Qb : Kb;
#pragma unroll
    for (int j = 0; j < 4; ++j) {
      int col = bnl + wn * 64 + j * 16 + l15;
      float bb = bias[col];
#pragma unroll
      for (int i = 0; i < 4; ++i) {
        int row0 = bm + wm * 64 + i * 16 + quad * 4;
#pragma unroll
        for (int r = 0; r < 4; ++r)
          O[(size_t)(row0 + r) * DM + col] = f2bf(acc[i][j][r] + bb);
      }
    }
  } else {
#pragma unroll
    for (int j = 0; j < 4; ++j) {
      int col = bnl + wn * 64 + j * 16 + l15;
      float bb = bias[col];
#pragma unroll
      for (int i = 0; i < 4; ++i) {
        int row0 = bm + wm * 64 + i * 16 + quad * 4;
        u32 lo = (u32)f2bf(acc[i][j][0] + bb) | ((u32)f2bf(acc[i][j][1] + bb) << 16);
        u32 hi = (u32)f2bf(acc[i][j][2] + bb) | ((u32)f2bf(acc[i][j][3] + bb) << 16);
        *(uint2*)&Vt[(size_t)col * BS_ + row0] = make_uint2(lo, hi);
      }
    }
  }
}

__global__ __launch_bounds__(256, 3) void gemm_wo(const u16* __restrict__ Cx,
    const u16* __restrict__ Wob, const float* __restrict__ bo, float* __restrict__ out) {
  __shared__ u16 As[8192], Bs[8192];
  const int bm = blockIdx.y * 128, bn = blockIdx.x * 128;
  f32x4 acc[4][4] = {};
  gemm_mainloop(Cx, Wob, bm, bn, As, Bs, acc);
  const int tid = threadIdx.x, wv = tid >> 6, lane = tid & 63, l15 = lane & 15, quad = lane >> 4;
  const int wm = wv & 1, wn = wv >> 1;
#pragma unroll
  for (int j = 0; j < 4; ++j) {
    int col = bn + wn * 64 + j * 16 + l15;
    float bb = bo[col];
#pragma unroll
    for (int i = 0; i < 4; ++i) {
      int row0 = bm + wm * 64 + i * 16 + quad * 4;
#pragma unroll
      for (int r = 0; r < 4; ++r)
        out[(size_t)(row0 + r) * DM + col] = acc[i][j][r] + bb;
    }
  }
}

// ---------------- Flash attention: barrier-free, static-max softmax ----------------
// grid (64, 32): 32-row q-strips (swizzled across CUs), 128 threads = 2 indep waves.
__global__ __launch_bounds__(128, 3) void attn_kernel(const u16* __restrict__ Q,
                                                      const u16* __restrict__ K,
                                                      const u16* __restrict__ Vt,
                                                      u16* __restrict__ Ctx) {
  __shared__ u16 Ps[2][16][76];   // per-wave P transpose; bank-disjoint quad sets

  const int tid = threadIdx.x, w = tid >> 6, lane = tid & 63, l15 = lane & 15, quad = lane >> 4;
  const int qt = (blockIdx.x + blockIdx.y) & 63;     // swizzle: spread heavy strips
  const int q0 = qt * 32;
  const int b = blockIdx.y >> 4, h = blockIdx.y & 15;
  const int qw = q0 + w * 16;

  const u16* qrow = Q + (size_t)(b * S_ + qw + l15) * DM + h * 64;
  frag8 aq0 = *(const frag8*)(qrow + quad * 8);
  frag8 aq1 = *(const frag8*)(qrow + quad * 8 + 32);

  // per-lane fragment base pointers (row l15, col-halves quad*8 / +32)
  const u16* kb = K  + (size_t)((size_t)b * S_ + l15) * DM + h * 64 + quad * 8;
  const u16* vb = Vt + (size_t)((size_t)h * 64 + l15) * BS_ + (size_t)b * S_ + quad * 8;

  int qidx[4]; bool qglob[4];
#pragma unroll
  for (int r = 0; r < 4; ++r) { qidx[r] = qw + quad * 4 + r; qglob[r] = qidx[r] < NG; }

  f32x4 o[4] = {};
  float lsum[4] = {0.f, 0.f, 0.f, 0.f};

  for (int kt = 0; kt < S_ / 64; ++kt) {
    const int k0 = kt * 64;
    bool active = (q0 < NG) || (k0 < NG) || (k0 + 63 >= q0 - 64 && k0 <= q0 + 31 + 64);
    if (!active) continue;

    // K B-frags (rows k0+kg*16+l15) — direct global b128
    const u16* kp = kb + (size_t)k0 * DM;
    frag8 bk[4][2];
#pragma unroll
    for (int kg = 0; kg < 4; ++kg) {
      bk[kg][0] = *(const frag8*)(kp + (size_t)(kg * 16) * DM);
      bk[kg][1] = *(const frag8*)(kp + (size_t)(kg * 16) * DM + 32);
    }
    // V^T B-frags issued early so latency overlaps softmax
    const u16* vp = vb + k0;
    frag8 bv[4][2];
#pragma unroll
    for (int nt = 0; nt < 4; ++nt) {
      bv[nt][0] = *(const frag8*)(vp + (size_t)(nt * 16) * BS_);
      bv[nt][1] = *(const frag8*)(vp + (size_t)(nt * 16) * BS_ + 32);
    }

    f32x4 sc[4] = {};
#pragma unroll
    for (int kg = 0; kg < 4; ++kg) {
      sc[kg] = MFMA16(aq0, bk[kg][0], sc[kg]);
      sc[kg] = MFMA16(aq1, bk[kg][1], sc[kg]);
    }

    // static-max softmax: p = exp2(s*SCL2), masked -> 0; l deferred per-lane
    float pr[4][4];
#pragma unroll
    for (int kg = 0; kg < 4; ++kg) {
      int kc = k0 + kg * 16 + l15;
      bool kglob = kc < NG;
#pragma unroll
      for (int r = 0; r < 4; ++r) {
        int d = qidx[r] - kc;
        bool act = ((unsigned)(d + 64) <= 128u) || qglob[r] || kglob;
        float s = act ? sc[kg][r] * SCL2 : NEGF;
        float p = EXP2(s);
        pr[kg][r] = p;
        lsum[r] += p;
      }
    }

    // P: C-layout -> wave-private LDS -> A-frags
#pragma unroll
    for (int kg = 0; kg < 4; ++kg)
#pragma unroll
      for (int r = 0; r < 4; ++r)
        Ps[w][quad * 4 + r][kg * 16 + l15] = f2bf(pr[kg][r]);
    __asm__ volatile("s_waitcnt lgkmcnt(0)" ::: "memory");
    frag8 ap0 = *(const frag8*)&Ps[w][l15][quad * 8];
    frag8 ap1 = *(const frag8*)&Ps[w][l15][quad * 8 + 32];

#pragma unroll
    for (int nt = 0; nt < 4; ++nt) {
      o[nt] = MFMA16(ap0, bv[nt][0], o[nt]);
      o[nt] = MFMA16(ap1, bv[nt][1], o[nt]);
    }
  }

  // one-time l reduction across the 16 lanes holding each row
#pragma unroll
  for (int off = 8; off; off >>= 1)
#pragma unroll
    for (int r = 0; r < 4; ++r) lsum[r] += __shfl_xor(lsum[r], off);

#pragma unroll
  for (int r = 0; r < 4; ++r) {
    float inv = 1.0f / lsum[r];
    int row = qw + quad * 4 + r;
    u16* crow = Ctx + (size_t)((size_t)b * S_ + row) * DM + h * 64;
#pragma unroll
    for (int nt = 0; nt < 4; ++nt)
      crow[nt * 16 + l15] = f2bf(o[nt][r] * inv);
  }
}

// ---------------- launch ----------------
extern "C" void kernel_launch(void* const* d_in, const int* in_sizes, int n_in,
                              void* d_out, int out_size, void* d_ws, size_t ws_size,
                              hipStream_t stream) {
  const float* X  = (const float*)d_in[0];
  const float* Wq = (const float*)d_in[1];
  const float* bq = (const float*)d_in[2];
  const float* Wk = (const float*)d_in[3];
  const float* bk = (const float*)d_in[4];
  const float* Wv = (const float*)d_in[5];
  const float* bv = (const float*)d_in[6];
  const float* Wo = (const float*)d_in[7];
  const float* bo = (const float*)d_in[8];
  float* out = (float*)d_out;

  u16* ws = (u16*)d_ws;
  const size_t NX = (size_t)BS_ * DM;
  const size_t NW = (size_t)DM * DM;
  u16* Xb  = ws;
  u16* Wqb = Xb + NX;
  u16* Wkb = Wqb + NW;
  u16* Wvb = Wkb + NW;
  u16* Wob = Wvb + NW;
  u16* Qb  = Wob + NW;
  u16* Kb  = Qb + NX;
  u16* Vt  = Kb + NX;
  u16* Cx  = Vt + NX;

  cvt_all<<<dim3(1024, 8), 256, 0, stream>>>(X, Wq, Wk, Wv, Wo, Xb, Wqb, Wkb, Wvb, Wob);
  gemm_qkv<<<dim3(24, 32), 256, 0, stream>>>(Xb, Wqb, Wkb, Wvb, bq, bk, bv, Qb, Kb, Vt);
  attn_kernel<<<dim3(64, 32), 128, 0, stream>>>(Qb, Kb, Vt, Cx);
  gemm_wo<<<dim3(8, 32), 256, 0, stream>>>(Cx, Wob, bo, out);
}

// Round 4
// 218.341 us; speedup vs baseline: 1.8264x; 1.0927x over previous
//
#include <hip/hip_runtime.h>

// LongformerAttention MI355X — Round 3.
// attn: software-pipelined (ping-pong K/V reg sets), XCD-pinned (b,h) mapping.
// gemm_wo: 512-thread blocks (8 waves/CU at 1 block/CU). qkv/cvt unchanged.

#define B_   2
#define S_   2048
#define DM   1024
#define H_   16
#define NG   204                     // max(1, int(S*0.1))
#define BS_  4096                    // B_*S_
#define SCL2 0.1803368801111204f     // (1/sqrt(64)) * log2(e)
#define NEGF -3.0e38f

typedef unsigned short u16;
typedef unsigned int   u32;
typedef __attribute__((ext_vector_type(8))) short frag8;   // 8 x bf16
typedef __attribute__((ext_vector_type(4))) float f32x4;

#define MFMA16(A, Bf, C) __builtin_amdgcn_mfma_f32_16x16x32_bf16((A), (Bf), (C), 0, 0, 0)
#define GLD16(g, l)                                                              \
  __builtin_amdgcn_global_load_lds((const __attribute__((address_space(1))) u32*)(g), \
                                   (__attribute__((address_space(3))) u32*)(l), 16, 0, 0)

#if __has_builtin(__builtin_amdgcn_exp2f)
#define EXP2(x) __builtin_amdgcn_exp2f(x)
#else
#define EXP2(x) exp2f(x)
#endif

__device__ __forceinline__ u16 f2bf(float f) {
  union { float f; u32 u; } c; c.f = f;
  u32 u = c.u + 0x7fffu + ((c.u >> 16) & 1u);   // RNE
  return (u16)(u >> 16);
}

// ---------------- fp32 -> bf16 convert, all buffers in one launch ----------------
__global__ void cvt_all(const float* __restrict__ X,  const float* __restrict__ Wq,
                        const float* __restrict__ Wk, const float* __restrict__ Wv,
                        const float* __restrict__ Wo,
                        u16* Xb, u16* Wqb, u16* Wkb, u16* Wvb, u16* Wob) {
  const int chunk = blockIdx.y;
  const float* src; u16* dst;
  if (chunk < 4)      { src = X + (size_t)chunk * 1048576; dst = Xb + (size_t)chunk * 1048576; }
  else if (chunk == 4){ src = Wq; dst = Wqb; }
  else if (chunk == 5){ src = Wk; dst = Wkb; }
  else if (chunk == 6){ src = Wv; dst = Wvb; }
  else                { src = Wo; dst = Wob; }
  int i = blockIdx.x * 256 + threadIdx.x;
  float4 v = ((const float4*)src)[i];
  u32 lo = (u32)f2bf(v.x) | ((u32)f2bf(v.y) << 16);
  u32 hi = (u32)f2bf(v.z) | ((u32)f2bf(v.w) << 16);
  ((uint2*)dst)[i] = make_uint2(lo, hi);
}

// ---------------- m97-style GEMM mainloop, 256 threads, 128x128 tile ----------------
__device__ __forceinline__ void gemm_mainloop(const u16* __restrict__ A, const u16* __restrict__ Bm,
                                              int bm, int bn, u16* As, u16* Bs,
                                              f32x4 acc[4][4]) {
  const int tid = threadIdx.x;
  const int wv = tid >> 6, lane = tid & 63, l15 = lane & 15, quad = lane >> 4;
  const int wm = wv & 1, wn = wv >> 1;

  const u16* gA[4]; const u16* gB[4];
#pragma unroll
  for (int c = 0; c < 4; ++c) {
    int idx = (wv * 4 + c) * 64 + lane;
    int r = idx >> 3;
    int cb = (idx & 7) ^ (r & 7);
    gA[c] = A  + (size_t)(bm + r) * DM + cb * 8;
    gB[c] = Bm + (size_t)(bn + r) * DM + cb * 8;
  }

  int offA[4][2], offB[4][2];
#pragma unroll
  for (int i = 0; i < 4; ++i)
#pragma unroll
    for (int h = 0; h < 2; ++h) {
      int mA = wm * 64 + i * 16 + l15;
      int mB = wn * 64 + i * 16 + l15;
      int cb = (quad + h * 4) ^ (l15 & 7);
      offA[i][h] = ((mA << 3) + cb) << 4;
      offB[i][h] = ((mB << 3) + cb) << 4;
    }

  for (int k0 = 0; k0 < DM; k0 += 64) {
#pragma unroll
    for (int c = 0; c < 4; ++c) {
      GLD16(gA[c] + k0, (char*)As + (wv * 4 + c) * 1024);
      GLD16(gB[c] + k0, (char*)Bs + (wv * 4 + c) * 1024);
    }
    __syncthreads();
    frag8 af[4][2], bf[4][2];
#pragma unroll
    for (int i = 0; i < 4; ++i) {
      af[i][0] = *(const frag8*)((const char*)As + offA[i][0]);
      af[i][1] = *(const frag8*)((const char*)As + offA[i][1]);
      bf[i][0] = *(const frag8*)((const char*)Bs + offB[i][0]);
      bf[i][1] = *(const frag8*)((const char*)Bs + offB[i][1]);
    }
#pragma unroll
    for (int h = 0; h < 2; ++h)
#pragma unroll
      for (int i = 0; i < 4; ++i)
#pragma unroll
        for (int j = 0; j < 4; ++j)
          acc[i][j] = MFMA16(af[i][h], bf[j][h], acc[i][j]);
    __syncthreads();
  }
}

__global__ __launch_bounds__(256, 3) void gemm_qkv(const u16* __restrict__ Xb,
    const u16* __restrict__ Wqb, const u16* __restrict__ Wkb, const u16* __restrict__ Wvb,
    const float* __restrict__ bq, const float* __restrict__ bk, const float* __restrict__ bv,
    u16* __restrict__ Qb, u16* __restrict__ Kb, u16* __restrict__ Vt) {
  __shared__ u16 As[8192], Bs[8192];
  const int bm = blockIdx.y * 128;
  const int which = blockIdx.x >> 3;
  const int bnl = (blockIdx.x & 7) * 128;
  const u16* W = (which == 0) ? Wqb : (which == 1) ? Wkb : Wvb;
  const float* bias = (which == 0) ? bq : (which == 1) ? bk : bv;

  f32x4 acc[4][4] = {};
  gemm_mainloop(Xb, W, bm, bnl, As, Bs, acc);

  const int tid = threadIdx.x, wv = tid >> 6, lane = tid & 63, l15 = lane & 15, quad = lane >> 4;
  const int wm = wv & 1, wn = wv >> 1;
  if (which < 2) {
    u16* O = (which == 0) ? Qb : Kb;
#pragma unroll
    for (int j = 0; j < 4; ++j) {
      int col = bnl + wn * 64 + j * 16 + l15;
      float bb = bias[col];
#pragma unroll
      for (int i = 0; i < 4; ++i) {
        int row0 = bm + wm * 64 + i * 16 + quad * 4;
#pragma unroll
        for (int r = 0; r < 4; ++r)
          O[(size_t)(row0 + r) * DM + col] = f2bf(acc[i][j][r] + bb);
      }
    }
  } else {
#pragma unroll
    for (int j = 0; j < 4; ++j) {
      int col = bnl + wn * 64 + j * 16 + l15;
      float bb = bias[col];
#pragma unroll
      for (int i = 0; i < 4; ++i) {
        int row0 = bm + wm * 64 + i * 16 + quad * 4;
        u32 lo = (u32)f2bf(acc[i][j][0] + bb) | ((u32)f2bf(acc[i][j][1] + bb) << 16);
        u32 hi = (u32)f2bf(acc[i][j][2] + bb) | ((u32)f2bf(acc[i][j][3] + bb) << 16);
        *(uint2*)&Vt[(size_t)col * BS_ + row0] = make_uint2(lo, hi);
      }
    }
  }
}

// ---------------- Wo GEMM: 512 threads (8 waves), 128x128 tile, waves 2m x 4n ----------------
__global__ __launch_bounds__(512, 2) void gemm_wo(const u16* __restrict__ Cx,
    const u16* __restrict__ Wob, const float* __restrict__ bo, float* __restrict__ out) {
  __shared__ u16 As[8192], Bs[8192];
  const int bm = blockIdx.y * 128, bn = blockIdx.x * 128;
  const int tid = threadIdx.x;
  const int wv = tid >> 6, lane = tid & 63, l15 = lane & 15, quad = lane >> 4;
  const int wm = wv & 1, wn = wv >> 1;   // wn 0..3 -> 32-col groups

  const u16* gA[2]; const u16* gB[2];
#pragma unroll
  for (int c = 0; c < 2; ++c) {
    int idx = (wv * 2 + c) * 64 + lane;
    int r = idx >> 3;
    int cb = (idx & 7) ^ (r & 7);
    gA[c] = Cx  + (size_t)(bm + r) * DM + cb * 8;
    gB[c] = Wob + (size_t)(bn + r) * DM + cb * 8;
  }
  int offA[4][2], offB[2][2];
#pragma unroll
  for (int h = 0; h < 2; ++h) {
#pragma unroll
    for (int i = 0; i < 4; ++i) {
      int mA = wm * 64 + i * 16 + l15;
      offA[i][h] = ((mA << 3) + ((quad + h * 4) ^ (l15 & 7))) << 4;
    }
#pragma unroll
    for (int j = 0; j < 2; ++j) {
      int nB = wn * 32 + j * 16 + l15;
      offB[j][h] = ((nB << 3) + ((quad + h * 4) ^ (l15 & 7))) << 4;
    }
  }

  f32x4 acc[4][2] = {};
  for (int k0 = 0; k0 < DM; k0 += 64) {
#pragma unroll
    for (int c = 0; c < 2; ++c) {
      GLD16(gA[c] + k0, (char*)As + (wv * 2 + c) * 1024);
      GLD16(gB[c] + k0, (char*)Bs + (wv * 2 + c) * 1024);
    }
    __syncthreads();
    frag8 af[4][2], bf[2][2];
#pragma unroll
    for (int i = 0; i < 4; ++i) {
      af[i][0] = *(const frag8*)((const char*)As + offA[i][0]);
      af[i][1] = *(const frag8*)((const char*)As + offA[i][1]);
    }
#pragma unroll
    for (int j = 0; j < 2; ++j) {
      bf[j][0] = *(const frag8*)((const char*)Bs + offB[j][0]);
      bf[j][1] = *(const frag8*)((const char*)Bs + offB[j][1]);
    }
#pragma unroll
    for (int h = 0; h < 2; ++h)
#pragma unroll
      for (int i = 0; i < 4; ++i)
#pragma unroll
        for (int j = 0; j < 2; ++j)
          acc[i][j] = MFMA16(af[i][h], bf[j][h], acc[i][j]);
    __syncthreads();
  }

#pragma unroll
  for (int j = 0; j < 2; ++j) {
    int col = bn + wn * 32 + j * 16 + l15;
    float bb = bo[col];
#pragma unroll
    for (int i = 0; i < 4; ++i) {
      int row0 = bm + wm * 64 + i * 16 + quad * 4;
#pragma unroll
      for (int r = 0; r < 4; ++r)
        out[(size_t)(row0 + r) * DM + col] = acc[i][j][r] + bb;
    }
  }
}

// ---------------- Flash attention: pipelined, barrier-free, XCD-pinned ----------------
// flat grid 2048: xcd = blk&7, slot = blk>>3; bh = xcd + 8*(slot&3); qt = slot>>2.
__global__ __launch_bounds__(128, 2) void attn_kernel(const u16* __restrict__ Q,
                                                      const u16* __restrict__ K,
                                                      const u16* __restrict__ Vt,
                                                      u16* __restrict__ Ctx) {
  __shared__ u16 Ps[2][16][76];

  const int tid = threadIdx.x, w = tid >> 6, lane = tid & 63, l15 = lane & 15, quad = lane >> 4;
  const int blk = blockIdx.x;
  const int xcd = blk & 7, slot = blk >> 3;
  const int bh = xcd + 8 * (slot & 3);
  const int qt = slot >> 2;
  const int q0 = qt * 32;
  const int b = bh >> 4, h = bh & 15;
  const int qw = q0 + w * 16;

  const u16* qrow = Q + (size_t)(b * S_ + qw + l15) * DM + h * 64;
  frag8 aq0 = *(const frag8*)(qrow + quad * 8);
  frag8 aq1 = *(const frag8*)(qrow + quad * 8 + 32);

  const u16* kb = K  + (size_t)((size_t)b * S_ + l15) * DM + h * 64 + quad * 8;
  const u16* vb = Vt + (size_t)((size_t)h * 64 + l15) * BS_ + (size_t)b * S_ + quad * 8;

  int qidx[4]; bool qglob[4];
#pragma unroll
  for (int r = 0; r < 4; ++r) { qidx[r] = qw + quad * 4 + r; qglob[r] = qidx[r] < NG; }

  f32x4 o[4] = {};
  float lsum[4] = {0.f, 0.f, 0.f, 0.f};

  auto activef = [&](int t) {
    int k0 = t * 64;
    return (q0 < NG) || (k0 < NG) || (k0 + 63 >= q0 - 64 && k0 <= q0 + 95);
  };
  auto nextt = [&](int cur) { int n = cur + 1; while (n < 32 && !activef(n)) ++n; return n; };

  auto loadK = [&](int t, frag8* d0, frag8* d1) {
    const u16* kp = kb + (size_t)(t * 64) * DM;
#pragma unroll
    for (int kg = 0; kg < 4; ++kg) {
      d0[kg] = *(const frag8*)(kp + (size_t)(kg * 16) * DM);
      d1[kg] = *(const frag8*)(kp + (size_t)(kg * 16) * DM + 32);
    }
  };
  auto loadV = [&](int t, frag8* d0, frag8* d1) {
    const u16* vp = vb + t * 64;
#pragma unroll
    for (int nt = 0; nt < 4; ++nt) {
      d0[nt] = *(const frag8*)(vp + (size_t)(nt * 16) * BS_);
      d1[nt] = *(const frag8*)(vp + (size_t)(nt * 16) * BS_ + 32);
    }
  };

  auto step = [&](int cur, int nxt, bool more,
                  frag8* bk0, frag8* bk1, frag8* bv0, frag8* bv1,
                  frag8* nk0, frag8* nk1, frag8* nv0, frag8* nv1) {
    const int k0 = cur * 64;
    f32x4 sc[4] = {};
#pragma unroll
    for (int kg = 0; kg < 4; ++kg) {
      sc[kg] = MFMA16(aq0, bk0[kg], sc[kg]);
      sc[kg] = MFMA16(aq1, bk1[kg], sc[kg]);
    }
    if (more) loadK(nxt, nk0, nk1);          // prefetch overlaps softmax+PV

    float pr[4][4];
#pragma unroll
    for (int kg = 0; kg < 4; ++kg) {
      int kc = k0 + kg * 16 + l15;
      bool kglob = kc < NG;
#pragma unroll
      for (int r = 0; r < 4; ++r) {
        int d = qidx[r] - kc;
        bool act = ((unsigned)(d + 64) <= 128u) || qglob[r] || kglob;
        float s = act ? sc[kg][r] * SCL2 : NEGF;
        float p = EXP2(s);
        pr[kg][r] = p;
        lsum[r] += p;
      }
    }
    if (more) loadV(nxt, nv0, nv1);          // prefetch overlaps P round-trip + PV

#pragma unroll
    for (int kg = 0; kg < 4; ++kg)
#pragma unroll
      for (int r = 0; r < 4; ++r)
        Ps[w][quad * 4 + r][kg * 16 + l15] = f2bf(pr[kg][r]);
    __asm__ volatile("s_waitcnt lgkmcnt(0)" ::: "memory");
    frag8 ap0 = *(const frag8*)&Ps[w][l15][quad * 8];
    frag8 ap1 = *(const frag8*)&Ps[w][l15][quad * 8 + 32];

#pragma unroll
    for (int nt = 0; nt < 4; ++nt) {
      o[nt] = MFMA16(ap0, bv0[nt], o[nt]);
      o[nt] = MFMA16(ap1, bv1[nt], o[nt]);
    }
  };

  frag8 Ak0[4], Ak1[4], Av0[4], Av1[4];
  frag8 Bk0[4], Bk1[4], Bv0[4], Bv1[4];
  int kt = 0;                              // tile 0 always active
  loadK(0, Ak0, Ak1);
  loadV(0, Av0, Av1);
  for (;;) {
    int ktn = nextt(kt);
    bool more = ktn < 32;
    step(kt, ktn, more, Ak0, Ak1, Av0, Av1, Bk0, Bk1, Bv0, Bv1);
    if (!more) break;
    kt = ktn;
    ktn = nextt(kt);
    more = ktn < 32;
    step(kt, ktn, more, Bk0, Bk1, Bv0, Bv1, Ak0, Ak1, Av0, Av1);
    if (!more) break;
    kt = ktn;
  }

#pragma unroll
  for (int off = 8; off; off >>= 1)
#pragma unroll
    for (int r = 0; r < 4; ++r) lsum[r] += __shfl_xor(lsum[r], off);

#pragma unroll
  for (int r = 0; r < 4; ++r) {
    float inv = 1.0f / lsum[r];
    int row = qw + quad * 4 + r;
    u16* crow = Ctx + (size_t)((size_t)b * S_ + row) * DM + h * 64;
#pragma unroll
    for (int nt = 0; nt < 4; ++nt)
      crow[nt * 16 + l15] = f2bf(o[nt][r] * inv);
  }
}

// ---------------- launch ----------------
extern "C" void kernel_launch(void* const* d_in, const int* in_sizes, int n_in,
                              void* d_out, int out_size, void* d_ws, size_t ws_size,
                              hipStream_t stream) {
  const float* X  = (const float*)d_in[0];
  const float* Wq = (const float*)d_in[1];
  const float* bq = (const float*)d_in[2];
  const float* Wk = (const float*)d_in[3];
  const float* bk = (const float*)d_in[4];
  const float* Wv = (const float*)d_in[5];
  const float* bv = (const float*)d_in[6];
  const float* Wo = (const float*)d_in[7];
  const float* bo = (const float*)d_in[8];
  float* out = (float*)d_out;

  u16* ws = (u16*)d_ws;
  const size_t NX = (size_t)BS_ * DM;
  const size_t NW = (size_t)DM * DM;
  u16* Xb  = ws;
  u16* Wqb = Xb + NX;
  u16* Wkb = Wqb + NW;
  u16* Wvb = Wkb + NW;
  u16* Wob = Wvb + NW;
  u16* Qb  = Wob + NW;
  u16* Kb  = Qb + NX;
  u16* Vt  = Kb + NX;
  u16* Cx  = Vt + NX;

  cvt_all<<<dim3(1024, 8), 256, 0, stream>>>(X, Wq, Wk, Wv, Wo, Xb, Wqb, Wkb, Wvb, Wob);
  gemm_qkv<<<dim3(24, 32), 256, 0, stream>>>(Xb, Wqb, Wkb, Wvb, bq, bk, bv, Qb, Kb, Vt);
  attn_kernel<<<2048, 128, 0, stream>>>(Qb, Kb, Vt, Cx);
  gemm_wo<<<dim3(8, 32), 512, 0, stream>>>(Cx, Wob, bo, out);
}